// Round 3
// baseline (584.283 us; speedup 1.0000x reference)
//
#include <hip/hip_runtime.h>
#include <math.h>

// Problem constants (B=4, N=10000 -> Nn=40000; IN=128, HID=OUT=64, H=2)
#define NN    40000
#define HEADS 2
#define CHN   64
#define NC    448   // packed cols: Q(128) | K(128) | V(128) | S(64)
#define KOFF  128
#define VOFF  256
#define SOFF  384

// ---- edge-index dtype detection: int64 stored LE has zero odd words ----
__global__ void detect_k(const int* __restrict__ w, int* __restrict__ flag) {
  if (threadIdx.x == 0 && blockIdx.x == 0) {
    int odd_or = 0;
    for (int i = 1; i < 512; i += 2) odd_or |= w[i];
    *flag = (odd_or == 0) ? 1 : 0;   // 1 => int64 layout, 0 => int32
  }
}

// ---- decode edges to int32 srcs/dsts + fused degree histogram ----
__global__ void decode_k(const int* __restrict__ w, const int* __restrict__ flag,
                         int* __restrict__ srcs, int* __restrict__ dsts,
                         int* __restrict__ deg, int E) {
  int e = blockIdx.x * blockDim.x + threadIdx.x;
  if (e >= E) return;
  int s, d;
  if (*flag) { s = w[2 * e]; d = w[2 * (E + e)]; }
  else       { s = w[e];     d = w[E + e]; }
  srcs[e] = s;
  dsts[e] = d;
  atomicAdd(&deg[d], 1);
}

// ---- pack both layers' Wq|Wk|Wv|Ws into B[K][448] (+biases) in ONE launch ----
__global__ void pack_all(const float* __restrict__ Wq1, const float* __restrict__ bq1,
                         const float* __restrict__ Wk1, const float* __restrict__ bk1,
                         const float* __restrict__ Wv1, const float* __restrict__ bv1,
                         const float* __restrict__ Ws1, const float* __restrict__ bs1,
                         const float* __restrict__ Wq2, const float* __restrict__ bq2,
                         const float* __restrict__ Wk2, const float* __restrict__ bk2,
                         const float* __restrict__ Wv2, const float* __restrict__ bv2,
                         const float* __restrict__ Ws2, const float* __restrict__ bs2,
                         float* __restrict__ B1, float* __restrict__ bias1,
                         float* __restrict__ B2, float* __restrict__ bias2) {
  int i = blockIdx.x * blockDim.x + threadIdx.x;
  if (i < 57344) {                    // layer-1 weights [128][448]
    int k = i / NC, c = i % NC;
    float v;
    if (c < 128)      v = Wq1[k * 128 + c];
    else if (c < 256) v = Wk1[k * 128 + (c - 128)];
    else if (c < 384) v = Wv1[k * 128 + (c - 256)];
    else              v = Ws1[k * 64 + (c - 384)];
    B1[i] = v;
  } else if (i < 86016) {             // layer-2 weights [64][448]
    int j = i - 57344;
    int k = j / NC, c = j % NC;
    float v;
    if (c < 128)      v = Wq2[k * 128 + c];
    else if (c < 256) v = Wk2[k * 128 + (c - 128)];
    else if (c < 384) v = Wv2[k * 128 + (c - 256)];
    else              v = Ws2[k * 64 + (c - 384)];
    B2[j] = v;
  } else if (i < 86464) {             // bias1
    int c = i - 86016;
    float v;
    if (c < 128)      v = bq1[c];
    else if (c < 256) v = bk1[c - 128];
    else if (c < 384) v = bv1[c - 256];
    else              v = bs1[c - 384];
    bias1[c] = v;
  } else if (i < 86912) {             // bias2
    int c = i - 86464;
    float v;
    if (c < 128)      v = bq2[c];
    else if (c < 256) v = bk2[c - 128];
    else if (c < 384) v = bv2[c - 256];
    else              v = bs2[c - 384];
    bias2[c] = v;
  }
}

// single-block scan; writes rp[0..n] AND cur[0..n-1] (scatter cursor copy)
__global__ void scan_k(const int* __restrict__ deg, int* __restrict__ rp,
                       int* __restrict__ cur, int n) {
  __shared__ int sums[1024];
  int tid = threadIdx.x;
  int per = (n + 1023) >> 10;
  int s0 = tid * per, s1 = min(s0 + per, n);
  int s = 0;
  for (int i = s0; i < s1; ++i) s += deg[i];
  sums[tid] = s;
  __syncthreads();
  for (int o = 1; o < 1024; o <<= 1) {
    int v = (tid >= o) ? sums[tid - o] : 0;
    __syncthreads();
    sums[tid] += v;
    __syncthreads();
  }
  int run = (tid == 0) ? 0 : sums[tid - 1];
  for (int i = s0; i < s1; ++i) { rp[i] = run; cur[i] = run; run += deg[i]; }
  if (tid == 1023) rp[n] = run;  // last chunk is empty => run == total == E
}

__global__ void scatter_k(const int* __restrict__ srcs, const int* __restrict__ dsts,
                          int* __restrict__ cur, int* __restrict__ col, int E) {
  int e = blockIdx.x * blockDim.x + threadIdx.x;
  if (e < E) {
    int p = atomicAdd(&cur[dsts[e]], 1);
    col[p] = srcs[e];
  }
}

// ---- f32 GEMM with fused bias: C[M][N] = A[M][K] @ B[K][N] + bias ----
// BM=BN=64, BK=32, 256 threads, 4x4 per thread. M%64==0, N%64==0, K%32==0.
__global__ __launch_bounds__(256) void gemm_bias(const float* __restrict__ A,
    const float* __restrict__ Bm, const float* __restrict__ bias,
    float* __restrict__ C, int M, int N, int K) {
  __shared__ __align__(16) float As[32][68];  // [k][m], padded
  __shared__ __align__(16) float Bs[32][64];  // [k][n]
  int bm = blockIdx.y << 6, bn = blockIdx.x << 6;
  int tid = threadIdx.x;
  int tr = (tid >> 4) << 2;   // 0..60
  int tc = (tid & 15) << 2;   // 0..60
  float acc[4][4] = {};
  for (int k0 = 0; k0 < K; k0 += 32) {
#pragma unroll
    for (int t = 0; t < 2; ++t) {
      int i = tid + (t << 8);            // 0..511
      int m = i >> 3, k4 = (i & 7) << 2; // A: 64 rows x 8 float4
      const float4 va = *(const float4*)(A + (size_t)(bm + m) * K + k0 + k4);
      As[k4 + 0][m] = va.x; As[k4 + 1][m] = va.y;
      As[k4 + 2][m] = va.z; As[k4 + 3][m] = va.w;
      int kb = i >> 4, n4 = (i & 15) << 2; // B: 32 rows x 16 float4
      *(float4*)&Bs[kb][n4] = *(const float4*)(Bm + (size_t)(k0 + kb) * N + bn + n4);
    }
    __syncthreads();
#pragma unroll
    for (int kk = 0; kk < 32; ++kk) {
      const float4 av = *(const float4*)&As[kk][tr];
      const float4 bv = *(const float4*)&Bs[kk][tc];
      float a[4] = {av.x, av.y, av.z, av.w};
      float b[4] = {bv.x, bv.y, bv.z, bv.w};
#pragma unroll
      for (int i2 = 0; i2 < 4; ++i2)
#pragma unroll
        for (int j = 0; j < 4; ++j) acc[i2][j] += a[i2] * b[j];
    }
    __syncthreads();
  }
  const float4 bb = *(const float4*)&bias[bn + tc];
#pragma unroll
  for (int i2 = 0; i2 < 4; ++i2) {
    float4 o;
    o.x = acc[i2][0] + bb.x; o.y = acc[i2][1] + bb.y;
    o.z = acc[i2][2] + bb.z; o.w = acc[i2][3] + bb.w;
    *(float4*)(C + (size_t)(bm + tr + i2) * N + bn + tc) = o;
  }
}

// ---- fused edge-softmax aggregation + head-mean + skip (+ leaky relu) ----
// one 128-thread block per dst node; wave h handles head h; online softmax.
__global__ __launch_bounds__(128) void agg_fused(const float* __restrict__ QKVS,
    const int* __restrict__ rp, const int* __restrict__ col,
    float* __restrict__ out, int act) {
  int dst = blockIdx.x;
  int h = threadIdx.x >> 6;    // 0 or 1
  int lane = threadIdx.x & 63;
  const float scale = 0.125f;  // 1/sqrt(64)
  float q = QKVS[(size_t)dst * NC + h * 64 + lane] * scale;
  float m = -INFINITY, d = 0.f, acc = 0.f;
  int e0 = rp[dst], e1 = rp[dst + 1];
  int src_n = (e0 < e1) ? col[e0] : 0;
  for (int e = e0; e < e1; ++e) {
    int src = src_n;
    if (e + 1 < e1) src_n = col[e + 1];          // prefetch next col
    const float* row = QKVS + (size_t)src * NC + h * 64 + lane;
    float kv = row[KOFF];
    float v  = row[VOFF];
    float p = q * kv;
#pragma unroll
    for (int o = 32; o; o >>= 1) p += __shfl_xor(p, o);
    float mn = fmaxf(m, p);
    float corr = __expf(m - mn);   // exp(-inf)=0 on first edge
    float w = __expf(p - mn);
    d = d * corr + w;
    acc = acc * corr + w * v;
    m = mn;
  }
  float r = acc / fmaxf(d, 1e-16f);
  __shared__ float s1[64];
  if (h == 1) s1[lane] = r;
  __syncthreads();
  if (h == 0) {
    float o = 0.5f * (r + s1[lane]) + QKVS[(size_t)dst * NC + SOFF + lane];
    if (act) o = o > 0.f ? o : 0.1f * o;
    out[(size_t)dst * CHN + lane] = o;
  }
}

extern "C" void kernel_launch(void* const* d_in, const int* in_sizes, int n_in,
                              void* d_out, int out_size, void* d_ws, size_t ws_size,
                              hipStream_t stream) {
  const float* x = (const float*)d_in[0];
  const int* ei_raw = (const int*)d_in[1];   // int32 OR int64 (runtime-detected)
  const float *Wq1 = (const float*)d_in[2],  *bq1 = (const float*)d_in[3],
              *Wk1 = (const float*)d_in[4],  *bk1 = (const float*)d_in[5],
              *Wv1 = (const float*)d_in[6],  *bv1 = (const float*)d_in[7],
              *Ws1 = (const float*)d_in[8],  *bs1 = (const float*)d_in[9],
              *Wq2 = (const float*)d_in[10], *bq2 = (const float*)d_in[11],
              *Wk2 = (const float*)d_in[12], *bk2 = (const float*)d_in[13],
              *Wv2 = (const float*)d_in[14], *bv2 = (const float*)d_in[15],
              *Ws2 = (const float*)d_in[16], *bs2 = (const float*)d_in[17];
  float* out = (float*)d_out;
  const int E = in_sizes[1] / 2;

  char* base = (char*)d_ws;
  size_t off = 0;
  auto take = [&](size_t bytes) {
    char* p = base + off;
    off += (bytes + 255) & ~(size_t)255;
    return p;
  };
  float* B1    = (float*)take((size_t)128 * NC * 4);
  float* bias1 = (float*)take(NC * 4);
  float* B2    = (float*)take((size_t)64 * NC * 4);
  float* bias2 = (float*)take(NC * 4);
  int*   flag  = (int*)take(256);
  int*   deg   = (int*)take((size_t)NN * 4);
  int*   rp    = (int*)take((size_t)(NN + 1) * 4);
  int*   cur   = (int*)take((size_t)(NN + 1) * 4);
  int*   srcs  = (int*)take((size_t)E * 4);
  int*   dsts  = (int*)take((size_t)E * 4);
  int*   col   = (int*)take((size_t)E * 4);
  float* QKVS  = (float*)take((size_t)NN * NC * 4);   // 71.7 MB, reused by both layers
  float* Hbuf  = (float*)take((size_t)NN * CHN * 4);
  (void)ws_size; (void)n_in; (void)out_size;

  // weight packing + edge decode + CSR build (same edge list for both layers)
  hipMemsetAsync(deg, 0, (size_t)NN * 4, stream);
  pack_all<<<(86912 + 255) / 256, 256, 0, stream>>>(
      Wq1, bq1, Wk1, bk1, Wv1, bv1, Ws1, bs1,
      Wq2, bq2, Wk2, bk2, Wv2, bv2, Ws2, bs2, B1, bias1, B2, bias2);
  detect_k<<<1, 64, 0, stream>>>(ei_raw, flag);
  decode_k<<<(E + 255) / 256, 256, 0, stream>>>(ei_raw, flag, srcs, dsts, deg, E);
  scan_k<<<1, 1024, 0, stream>>>(deg, rp, cur, NN);
  scatter_k<<<(E + 255) / 256, 256, 0, stream>>>(srcs, dsts, cur, col, E);

  // layer 1: x[40000x128] -> QKVS -> fused agg -> Hbuf (leaky relu)
  gemm_bias<<<dim3(NC / 64, NN / 64), 256, 0, stream>>>(x, B1, bias1, QKVS, NN, NC, 128);
  agg_fused<<<NN, 128, 0, stream>>>(QKVS, rp, col, Hbuf, 1);

  // layer 2: Hbuf[40000x64] -> QKVS -> fused agg -> out (no activation)
  gemm_bias<<<dim3(NC / 64, NN / 64), 256, 0, stream>>>(Hbuf, B2, bias2, QKVS, NN, NC, 64);
  agg_fused<<<NN, 128, 0, stream>>>(QKVS, rp, col, out, 0);
}

// Round 4
// 548.747 us; speedup vs baseline: 1.0648x; 1.0648x over previous
//
#include <hip/hip_runtime.h>
#include <math.h>

// Problem constants (B=4, N=10000 -> Nn=40000; IN=128, HID=OUT=64, H=2)
#define NN    40000
#define HEADS 2
#define CHN   64
#define NC    448   // packed cols: Q(128) | K(128) | V(128) | S(64)
#define KOFF  128
#define VOFF  256
#define SOFF  384

// ---- edge-index dtype detection: int64 stored LE has zero odd words ----
// wave-parallel: lane i ORs odd words of the first 256 int64 slots
__global__ void detect_k(const int* __restrict__ w, int* __restrict__ flag) {
  int lane = threadIdx.x & 63;
  int v = 0;
#pragma unroll
  for (int i = 0; i < 4; ++i) v |= w[2 * (lane + 64 * i) + 1];
#pragma unroll
  for (int o = 32; o; o >>= 1) v |= __shfl_xor(v, o);
  if (lane == 0 && blockIdx.x == 0) *flag = (v == 0) ? 1 : 0;
}

// ---- decode edges to int32 srcs/dsts + fused degree histogram ----
__global__ void decode_k(const int* __restrict__ w, const int* __restrict__ flag,
                         int* __restrict__ srcs, int* __restrict__ dsts,
                         int* __restrict__ deg, int E) {
  int e = blockIdx.x * blockDim.x + threadIdx.x;
  if (e >= E) return;
  int s, d;
  if (*flag) { s = w[2 * e]; d = w[2 * (E + e)]; }
  else       { s = w[e];     d = w[E + e]; }
  srcs[e] = s;
  dsts[e] = d;
  atomicAdd(&deg[d], 1);
}

// ---- pack both layers' Wq|Wk|Wv|Ws into B[K][448] (+biases) in ONE launch ----
__global__ void pack_all(const float* __restrict__ Wq1, const float* __restrict__ bq1,
                         const float* __restrict__ Wk1, const float* __restrict__ bk1,
                         const float* __restrict__ Wv1, const float* __restrict__ bv1,
                         const float* __restrict__ Ws1, const float* __restrict__ bs1,
                         const float* __restrict__ Wq2, const float* __restrict__ bq2,
                         const float* __restrict__ Wk2, const float* __restrict__ bk2,
                         const float* __restrict__ Wv2, const float* __restrict__ bv2,
                         const float* __restrict__ Ws2, const float* __restrict__ bs2,
                         float* __restrict__ B1, float* __restrict__ bias1,
                         float* __restrict__ B2, float* __restrict__ bias2) {
  int i = blockIdx.x * blockDim.x + threadIdx.x;
  if (i < 57344) {                    // layer-1 weights [128][448]
    int k = i / NC, c = i % NC;
    float v;
    if (c < 128)      v = Wq1[k * 128 + c];
    else if (c < 256) v = Wk1[k * 128 + (c - 128)];
    else if (c < 384) v = Wv1[k * 128 + (c - 256)];
    else              v = Ws1[k * 64 + (c - 384)];
    B1[i] = v;
  } else if (i < 86016) {             // layer-2 weights [64][448]
    int j = i - 57344;
    int k = j / NC, c = j % NC;
    float v;
    if (c < 128)      v = Wq2[k * 128 + c];
    else if (c < 256) v = Wk2[k * 128 + (c - 128)];
    else if (c < 384) v = Wv2[k * 128 + (c - 256)];
    else              v = Ws2[k * 64 + (c - 384)];
    B2[j] = v;
  } else if (i < 86464) {             // bias1
    int c = i - 86016;
    float v;
    if (c < 128)      v = bq1[c];
    else if (c < 256) v = bk1[c - 128];
    else if (c < 384) v = bv1[c - 256];
    else              v = bs1[c - 384];
    bias1[c] = v;
  } else if (i < 86912) {             // bias2
    int c = i - 86464;
    float v;
    if (c < 128)      v = bq2[c];
    else if (c < 256) v = bk2[c - 128];
    else if (c < 384) v = bv2[c - 256];
    else              v = bs2[c - 384];
    bias2[c] = v;
  }
}

// single-block scan; writes rp[0..n] AND cur[0..n-1] (scatter cursor copy)
__global__ void scan_k(const int* __restrict__ deg, int* __restrict__ rp,
                       int* __restrict__ cur, int n) {
  __shared__ int sums[1024];
  int tid = threadIdx.x;
  int per = (n + 1023) >> 10;
  int s0 = tid * per, s1 = min(s0 + per, n);
  int s = 0;
  for (int i = s0; i < s1; ++i) s += deg[i];
  sums[tid] = s;
  __syncthreads();
  for (int o = 1; o < 1024; o <<= 1) {
    int v = (tid >= o) ? sums[tid - o] : 0;
    __syncthreads();
    sums[tid] += v;
    __syncthreads();
  }
  int run = (tid == 0) ? 0 : sums[tid - 1];
  for (int i = s0; i < s1; ++i) { rp[i] = run; cur[i] = run; run += deg[i]; }
  if (tid == 1023) rp[n] = run;  // last chunk is empty => run == total == E
}

__global__ void scatter_k(const int* __restrict__ srcs, const int* __restrict__ dsts,
                          int* __restrict__ cur, int* __restrict__ col, int E) {
  int e = blockIdx.x * blockDim.x + threadIdx.x;
  if (e < E) {
    int p = atomicAdd(&cur[dsts[e]], 1);
    col[p] = srcs[e];
  }
}

// ---- f32 GEMM with fused bias: C[M][N] = A[M][K] @ B[K][N] + bias ----
// BM=BN=64, BK=32, 256 threads, 4x4 per thread. M%64==0, N%64==0, K%32==0.
__global__ __launch_bounds__(256) void gemm_bias(const float* __restrict__ A,
    const float* __restrict__ Bm, const float* __restrict__ bias,
    float* __restrict__ C, int M, int N, int K) {
  __shared__ __align__(16) float As[32][68];  // [k][m], padded
  __shared__ __align__(16) float Bs[32][64];  // [k][n]
  int bm = blockIdx.y << 6, bn = blockIdx.x << 6;
  int tid = threadIdx.x;
  int tr = (tid >> 4) << 2;   // 0..60
  int tc = (tid & 15) << 2;   // 0..60
  float acc[4][4] = {};
  for (int k0 = 0; k0 < K; k0 += 32) {
#pragma unroll
    for (int t = 0; t < 2; ++t) {
      int i = tid + (t << 8);            // 0..511
      int m = i >> 3, k4 = (i & 7) << 2; // A: 64 rows x 8 float4
      const float4 va = *(const float4*)(A + (size_t)(bm + m) * K + k0 + k4);
      As[k4 + 0][m] = va.x; As[k4 + 1][m] = va.y;
      As[k4 + 2][m] = va.z; As[k4 + 3][m] = va.w;
      int kb = i >> 4, n4 = (i & 15) << 2; // B: 32 rows x 16 float4
      *(float4*)&Bs[kb][n4] = *(const float4*)(Bm + (size_t)(k0 + kb) * N + bn + n4);
    }
    __syncthreads();
#pragma unroll
    for (int kk = 0; kk < 32; ++kk) {
      const float4 av = *(const float4*)&As[kk][tr];
      const float4 bv = *(const float4*)&Bs[kk][tc];
      float a[4] = {av.x, av.y, av.z, av.w};
      float b[4] = {bv.x, bv.y, bv.z, bv.w};
#pragma unroll
      for (int i2 = 0; i2 < 4; ++i2)
#pragma unroll
        for (int j = 0; j < 4; ++j) acc[i2][j] += a[i2] * b[j];
    }
    __syncthreads();
  }
  const float4 bb = *(const float4*)&bias[bn + tc];
#pragma unroll
  for (int i2 = 0; i2 < 4; ++i2) {
    float4 o;
    o.x = acc[i2][0] + bb.x; o.y = acc[i2][1] + bb.y;
    o.z = acc[i2][2] + bb.z; o.w = acc[i2][3] + bb.w;
    *(float4*)(C + (size_t)(bm + tr + i2) * N + bn + tc) = o;
  }
}

// ---- fused edge-softmax aggregation + head-mean + skip (+ leaky relu) ----
// one 128-thread block per dst node; wave h handles head h; online softmax.
// Software-pipelined: unroll x2, K/V loads for edges e+2,e+3 issued before
// computing e,e+1; col indices prefetched 4-5 ahead (clamped, branch-free).
__global__ __launch_bounds__(128) void agg_fused(const float* __restrict__ QKVS,
    const int* __restrict__ rp, const int* __restrict__ col,
    float* __restrict__ out, int act) {
  int dst = blockIdx.x;
  int h = threadIdx.x >> 6;    // 0 or 1
  int lane = threadIdx.x & 63;
  const float scale = 0.125f;  // 1/sqrt(64)
  const float* __restrict__ base = QKVS + h * 64 + lane;
  float q = QKVS[(size_t)dst * NC + h * 64 + lane] * scale;
  float m = -INFINITY, d = 0.f, acc = 0.f;
  int e0 = rp[dst], e1 = rp[dst + 1];

  auto step = [&](float kv, float v) {
    float p = q * kv;
#pragma unroll
    for (int o = 32; o; o >>= 1) p += __shfl_xor(p, o);
    float mn = fmaxf(m, p);
    float corr = __expf(m - mn);   // exp(-inf)=0 on first edge
    float w = __expf(p - mn);
    d = d * corr + w;
    acc = acc * corr + w * v;
    m = mn;
  };

  if (e0 < e1) {
    int last = e1 - 1;
    // cols for first 4 edges (clamped to valid range, branch-free)
    int sC = col[min(e0 + 2, last)];
    int sD = col[min(e0 + 3, last)];
    {
      int sA = col[e0];
      int sB = col[min(e0 + 1, last)];
      const float* rA = base + (size_t)sA * NC;
      const float* rB = base + (size_t)sB * NC;
      float k0 = rA[KOFF], v0 = rA[VOFF];
      float k1 = rB[KOFF], v1 = rB[VOFF];
      int e = e0;
      for (; e + 1 < e1; e += 2) {
        // issue loads for the NEXT pair before consuming the current one
        const float* rC = base + (size_t)sC * NC;
        const float* rD = base + (size_t)sD * NC;
        float k2 = rC[KOFF], v2 = rC[VOFF];
        float k3 = rD[KOFF], v3 = rD[VOFF];
        sC = col[min(e + 4, last)];
        sD = col[min(e + 5, last)];
        step(k0, v0);
        step(k1, v1);
        k0 = k2; v0 = v2; k1 = k3; v1 = v3;
      }
      if (e < e1) step(k0, v0);   // odd-degree tail
    }
  }

  float r = acc / fmaxf(d, 1e-16f);
  __shared__ float s1[64];
  if (h == 1) s1[lane] = r;
  __syncthreads();
  if (h == 0) {
    float o = 0.5f * (r + s1[lane]) + QKVS[(size_t)dst * NC + SOFF + lane];
    if (act) o = o > 0.f ? o : 0.1f * o;
    out[(size_t)dst * CHN + lane] = o;
  }
}

extern "C" void kernel_launch(void* const* d_in, const int* in_sizes, int n_in,
                              void* d_out, int out_size, void* d_ws, size_t ws_size,
                              hipStream_t stream) {
  const float* x = (const float*)d_in[0];
  const int* ei_raw = (const int*)d_in[1];   // int32 OR int64 (runtime-detected)
  const float *Wq1 = (const float*)d_in[2],  *bq1 = (const float*)d_in[3],
              *Wk1 = (const float*)d_in[4],  *bk1 = (const float*)d_in[5],
              *Wv1 = (const float*)d_in[6],  *bv1 = (const float*)d_in[7],
              *Ws1 = (const float*)d_in[8],  *bs1 = (const float*)d_in[9],
              *Wq2 = (const float*)d_in[10], *bq2 = (const float*)d_in[11],
              *Wk2 = (const float*)d_in[12], *bk2 = (const float*)d_in[13],
              *Wv2 = (const float*)d_in[14], *bv2 = (const float*)d_in[15],
              *Ws2 = (const float*)d_in[16], *bs2 = (const float*)d_in[17];
  float* out = (float*)d_out;
  const int E = in_sizes[1] / 2;

  char* base = (char*)d_ws;
  size_t off = 0;
  auto take = [&](size_t bytes) {
    char* p = base + off;
    off += (bytes + 255) & ~(size_t)255;
    return p;
  };
  float* B1    = (float*)take((size_t)128 * NC * 4);
  float* bias1 = (float*)take(NC * 4);
  float* B2    = (float*)take((size_t)64 * NC * 4);
  float* bias2 = (float*)take(NC * 4);
  int*   flag  = (int*)take(256);
  int*   deg   = (int*)take((size_t)NN * 4);
  int*   rp    = (int*)take((size_t)(NN + 1) * 4);
  int*   cur   = (int*)take((size_t)(NN + 1) * 4);
  int*   srcs  = (int*)take((size_t)E * 4);
  int*   dsts  = (int*)take((size_t)E * 4);
  int*   col   = (int*)take((size_t)E * 4);
  float* QKVS  = (float*)take((size_t)NN * NC * 4);   // 71.7 MB, reused by both layers
  float* Hbuf  = (float*)take((size_t)NN * CHN * 4);
  (void)ws_size; (void)n_in; (void)out_size;

  // weight packing + edge decode + CSR build (same edge list for both layers)
  hipMemsetAsync(deg, 0, (size_t)NN * 4, stream);
  pack_all<<<(86912 + 255) / 256, 256, 0, stream>>>(
      Wq1, bq1, Wk1, bk1, Wv1, bv1, Ws1, bs1,
      Wq2, bq2, Wk2, bk2, Wv2, bv2, Ws2, bs2, B1, bias1, B2, bias2);
  detect_k<<<1, 64, 0, stream>>>(ei_raw, flag);
  decode_k<<<(E + 255) / 256, 256, 0, stream>>>(ei_raw, flag, srcs, dsts, deg, E);
  scan_k<<<1, 1024, 0, stream>>>(deg, rp, cur, NN);
  scatter_k<<<(E + 255) / 256, 256, 0, stream>>>(srcs, dsts, cur, col, E);

  // layer 1: x[40000x128] -> QKVS -> fused agg -> Hbuf (leaky relu)
  gemm_bias<<<dim3(NC / 64, NN / 64), 256, 0, stream>>>(x, B1, bias1, QKVS, NN, NC, 128);
  agg_fused<<<NN, 128, 0, stream>>>(QKVS, rp, col, Hbuf, 1);

  // layer 2: Hbuf[40000x64] -> QKVS -> fused agg -> out (no activation)
  gemm_bias<<<dim3(NC / 64, NN / 64), 256, 0, stream>>>(Hbuf, B2, bias2, QKVS, NN, NC, 64);
  agg_fused<<<NN, 128, 0, stream>>>(QKVS, rp, col, out, 0);
}

// Round 5
// 520.118 us; speedup vs baseline: 1.1234x; 1.0550x over previous
//
#include <hip/hip_runtime.h>
#include <math.h>

// Problem constants (B=4, N=10000 -> Nn=40000; IN=128, HID=OUT=64, H=2)
#define NN    40000
#define HEADS 2
#define CHN   64
#define NC    448   // packed cols: Q(128) | K(128) | V(128) | S(64)
#define KOFF  128
#define VOFF  256
#define SOFF  384

// ---- edge-index dtype detection: int64 stored LE has zero odd words ----
__global__ void detect_k(const int* __restrict__ w, int* __restrict__ flag) {
  int lane = threadIdx.x & 63;
  int v = 0;
#pragma unroll
  for (int i = 0; i < 4; ++i) v |= w[2 * (lane + 64 * i) + 1];
#pragma unroll
  for (int o = 32; o; o >>= 1) v |= __shfl_xor(v, o);
  if (lane == 0 && blockIdx.x == 0) *flag = (v == 0) ? 1 : 0;
}

// ---- decode edges to int32 srcs/dsts + fused degree histogram ----
__global__ void decode_k(const int* __restrict__ w, const int* __restrict__ flag,
                         int* __restrict__ srcs, int* __restrict__ dsts,
                         int* __restrict__ deg, int E) {
  int e = blockIdx.x * blockDim.x + threadIdx.x;
  if (e >= E) return;
  int s, d;
  if (*flag) { s = w[2 * e]; d = w[2 * (E + e)]; }
  else       { s = w[e];     d = w[E + e]; }
  srcs[e] = s;
  dsts[e] = d;
  atomicAdd(&deg[d], 1);
}

// ---- pack both layers' Wq|Wk|Wv|Ws into B[K][448] (+biases) in ONE launch ----
__global__ void pack_all(const float* __restrict__ Wq1, const float* __restrict__ bq1,
                         const float* __restrict__ Wk1, const float* __restrict__ bk1,
                         const float* __restrict__ Wv1, const float* __restrict__ bv1,
                         const float* __restrict__ Ws1, const float* __restrict__ bs1,
                         const float* __restrict__ Wq2, const float* __restrict__ bq2,
                         const float* __restrict__ Wk2, const float* __restrict__ bk2,
                         const float* __restrict__ Wv2, const float* __restrict__ bv2,
                         const float* __restrict__ Ws2, const float* __restrict__ bs2,
                         float* __restrict__ B1, float* __restrict__ bias1,
                         float* __restrict__ B2, float* __restrict__ bias2) {
  int i = blockIdx.x * blockDim.x + threadIdx.x;
  if (i < 57344) {                    // layer-1 weights [128][448]
    int k = i / NC, c = i % NC;
    float v;
    if (c < 128)      v = Wq1[k * 128 + c];
    else if (c < 256) v = Wk1[k * 128 + (c - 128)];
    else if (c < 384) v = Wv1[k * 128 + (c - 256)];
    else              v = Ws1[k * 64 + (c - 384)];
    B1[i] = v;
  } else if (i < 86016) {             // layer-2 weights [64][448]
    int j = i - 57344;
    int k = j / NC, c = j % NC;
    float v;
    if (c < 128)      v = Wq2[k * 128 + c];
    else if (c < 256) v = Wk2[k * 128 + (c - 128)];
    else if (c < 384) v = Wv2[k * 128 + (c - 256)];
    else              v = Ws2[k * 64 + (c - 384)];
    B2[j] = v;
  } else if (i < 86464) {             // bias1
    int c = i - 86016;
    float v;
    if (c < 128)      v = bq1[c];
    else if (c < 256) v = bk1[c - 128];
    else if (c < 384) v = bv1[c - 256];
    else              v = bs1[c - 384];
    bias1[c] = v;
  } else if (i < 86912) {             // bias2
    int c = i - 86464;
    float v;
    if (c < 128)      v = bq2[c];
    else if (c < 256) v = bk2[c - 128];
    else if (c < 384) v = bv2[c - 256];
    else              v = bs2[c - 384];
    bias2[c] = v;
  }
}

// single-block scan; writes rp[0..n] AND cur[0..n-1] (scatter cursor copy)
__global__ void scan_k(const int* __restrict__ deg, int* __restrict__ rp,
                       int* __restrict__ cur, int n) {
  __shared__ int sums[1024];
  int tid = threadIdx.x;
  int per = (n + 1023) >> 10;
  int s0 = tid * per, s1 = min(s0 + per, n);
  int s = 0;
  for (int i = s0; i < s1; ++i) s += deg[i];
  sums[tid] = s;
  __syncthreads();
  for (int o = 1; o < 1024; o <<= 1) {
    int v = (tid >= o) ? sums[tid - o] : 0;
    __syncthreads();
    sums[tid] += v;
    __syncthreads();
  }
  int run = (tid == 0) ? 0 : sums[tid - 1];
  for (int i = s0; i < s1; ++i) { rp[i] = run; cur[i] = run; run += deg[i]; }
  if (tid == 1023) rp[n] = run;  // last chunk is empty => run == total == E
}

__global__ void scatter_k(const int* __restrict__ srcs, const int* __restrict__ dsts,
                          int* __restrict__ cur, int* __restrict__ col, int E) {
  int e = blockIdx.x * blockDim.x + threadIdx.x;
  if (e < E) {
    int p = atomicAdd(&cur[dsts[e]], 1);
    col[p] = srcs[e];
  }
}

// ---- f32 GEMM with fused bias: C[M][N] = A[M][K] @ B[K][N] + bias ----
// BM=BN=64, BK=32, 256 threads, 4x4 per thread. M%64==0, N%64==0, K%32==0.
__global__ __launch_bounds__(256) void gemm_bias(const float* __restrict__ A,
    const float* __restrict__ Bm, const float* __restrict__ bias,
    float* __restrict__ C, int M, int N, int K) {
  __shared__ __align__(16) float As[32][68];  // [k][m], padded
  __shared__ __align__(16) float Bs[32][64];  // [k][n]
  int bm = blockIdx.y << 6, bn = blockIdx.x << 6;
  int tid = threadIdx.x;
  int tr = (tid >> 4) << 2;   // 0..60
  int tc = (tid & 15) << 2;   // 0..60
  float acc[4][4] = {};
  for (int k0 = 0; k0 < K; k0 += 32) {
#pragma unroll
    for (int t = 0; t < 2; ++t) {
      int i = tid + (t << 8);            // 0..511
      int m = i >> 3, k4 = (i & 7) << 2; // A: 64 rows x 8 float4
      const float4 va = *(const float4*)(A + (size_t)(bm + m) * K + k0 + k4);
      As[k4 + 0][m] = va.x; As[k4 + 1][m] = va.y;
      As[k4 + 2][m] = va.z; As[k4 + 3][m] = va.w;
      int kb = i >> 4, n4 = (i & 15) << 2; // B: 32 rows x 16 float4
      *(float4*)&Bs[kb][n4] = *(const float4*)(Bm + (size_t)(k0 + kb) * N + bn + n4);
    }
    __syncthreads();
#pragma unroll
    for (int kk = 0; kk < 32; ++kk) {
      const float4 av = *(const float4*)&As[kk][tr];
      const float4 bv = *(const float4*)&Bs[kk][tc];
      float a[4] = {av.x, av.y, av.z, av.w};
      float b[4] = {bv.x, bv.y, bv.z, bv.w};
#pragma unroll
      for (int i2 = 0; i2 < 4; ++i2)
#pragma unroll
        for (int j = 0; j < 4; ++j) acc[i2][j] += a[i2] * b[j];
    }
    __syncthreads();
  }
  const float4 bb = *(const float4*)&bias[bn + tc];
#pragma unroll
  for (int i2 = 0; i2 < 4; ++i2) {
    float4 o;
    o.x = acc[i2][0] + bb.x; o.y = acc[i2][1] + bb.y;
    o.z = acc[i2][2] + bb.z; o.w = acc[i2][3] + bb.w;
    *(float4*)(C + (size_t)(bm + tr + i2) * N + bn + tc) = o;
  }
}

// ---- fused edge-softmax aggregation + head-mean + skip (+ leaky relu) ----
// one 128-thread block per dst node; wave h = head h.
// Wave is split into 4 groups of 16 lanes; each group processes its own edge
// stream (e0+g, e0+g+4, ...) with an independent online-softmax state and
// float4-per-lane channels (16 lanes x 4 = 64 ch). Depth-2 K/V prefetch.
// Group states are merged with a flash-style xor-16/32 butterfly at the end.
__global__ __launch_bounds__(128) void agg_fused(const float* __restrict__ QKVS,
    const int* __restrict__ rp, const int* __restrict__ col,
    float* __restrict__ out, int act) {
  int dst = blockIdx.x;
  int h = threadIdx.x >> 6;    // 0 or 1
  int lane = threadIdx.x & 63;
  int g = lane >> 4;           // group 0..3
  int sl = lane & 15;          // sublane: channels 4*sl .. 4*sl+3
  const float scale = 0.125f;  // 1/sqrt(64)

  float4 q4 = *(const float4*)(QKVS + (size_t)dst * NC + h * 64 + 4 * sl);
  q4.x *= scale; q4.y *= scale; q4.z *= scale; q4.w *= scale;
  const float* __restrict__ base = QKVS + h * 64 + 4 * sl;

  float m = -INFINITY, d = 0.f;
  float4 acc = {0.f, 0.f, 0.f, 0.f};
  int e0 = rp[dst], e1 = rp[dst + 1];

  int e = e0 + g;
  if (e < e1) {
    int sCur = col[e];
    int en = e + 4;
    int sNxt = (en < e1) ? col[en] : sCur;
    const float* rC = base + (size_t)sCur * NC;
    float4 kC = *(const float4*)(rC + KOFF);
    float4 vC = *(const float4*)(rC + VOFF);
    while (true) {
      // issue next edge's K/V + next-next col before consuming current
      const float* rN = base + (size_t)sNxt * NC;
      float4 kN = *(const float4*)(rN + KOFF);
      float4 vN = *(const float4*)(rN + VOFF);
      int enn = e + 8;
      int sNN = (enn < e1) ? col[enn] : sNxt;
      // logit: group-local 16-lane dot (4 FMA + 4 hops)
      float p = q4.x * kC.x + q4.y * kC.y + q4.z * kC.z + q4.w * kC.w;
      p += __shfl_xor(p, 1); p += __shfl_xor(p, 2);
      p += __shfl_xor(p, 4); p += __shfl_xor(p, 8);
      float mn = fmaxf(m, p);
      float corr = __expf(m - mn);   // first edge: exp(-inf)=0
      float w = __expf(p - mn);
      d = d * corr + w;
      acc.x = acc.x * corr + w * vC.x;
      acc.y = acc.y * corr + w * vC.y;
      acc.z = acc.z * corr + w * vC.z;
      acc.w = acc.w * corr + w * vC.w;
      m = mn;
      e += 4;
      if (e >= e1) break;
      kC = kN; vC = vN; sNxt = sNN;
    }
  }

  // merge the 4 group states (butterfly over xor 16, 32 -> allreduce)
#pragma unroll
  for (int o = 16; o <= 32; o <<= 1) {
    float m2 = __shfl_xor(m, o);
    float d2 = __shfl_xor(d, o);
    float ax = __shfl_xor(acc.x, o), ay = __shfl_xor(acc.y, o);
    float az = __shfl_xor(acc.z, o), aw = __shfl_xor(acc.w, o);
    float mn = fmaxf(m, m2);
    // fmaxf drops the NaN from (-inf)-(-inf) for empty groups -> corr 0
    float c1 = __expf(fmaxf(m - mn, -88.f));
    float c2 = __expf(fmaxf(m2 - mn, -88.f));
    d = d * c1 + d2 * c2;
    acc.x = acc.x * c1 + ax * c2;
    acc.y = acc.y * c1 + ay * c2;
    acc.z = acc.z * c1 + az * c2;
    acc.w = acc.w * c1 + aw * c2;
    m = mn;
  }
  float inv = 1.0f / fmaxf(d, 1e-16f);
  float4 r = {acc.x * inv, acc.y * inv, acc.z * inv, acc.w * inv};

  __shared__ float s1[64];
  if (h == 1 && g == 0) *(float4*)&s1[4 * sl] = r;
  __syncthreads();
  if (h == 0 && g == 0) {
    const float4 rr = *(const float4*)&s1[4 * sl];
    const float4 sk = *(const float4*)(QKVS + (size_t)dst * NC + SOFF + 4 * sl);
    float4 o;
    o.x = 0.5f * (r.x + rr.x) + sk.x;
    o.y = 0.5f * (r.y + rr.y) + sk.y;
    o.z = 0.5f * (r.z + rr.z) + sk.z;
    o.w = 0.5f * (r.w + rr.w) + sk.w;
    if (act) {
      o.x = o.x > 0.f ? o.x : 0.1f * o.x;
      o.y = o.y > 0.f ? o.y : 0.1f * o.y;
      o.z = o.z > 0.f ? o.z : 0.1f * o.z;
      o.w = o.w > 0.f ? o.w : 0.1f * o.w;
    }
    *(float4*)(out + (size_t)dst * CHN + 4 * sl) = o;
  }
}

extern "C" void kernel_launch(void* const* d_in, const int* in_sizes, int n_in,
                              void* d_out, int out_size, void* d_ws, size_t ws_size,
                              hipStream_t stream) {
  const float* x = (const float*)d_in[0];
  const int* ei_raw = (const int*)d_in[1];   // int32 OR int64 (runtime-detected)
  const float *Wq1 = (const float*)d_in[2],  *bq1 = (const float*)d_in[3],
              *Wk1 = (const float*)d_in[4],  *bk1 = (const float*)d_in[5],
              *Wv1 = (const float*)d_in[6],  *bv1 = (const float*)d_in[7],
              *Ws1 = (const float*)d_in[8],  *bs1 = (const float*)d_in[9],
              *Wq2 = (const float*)d_in[10], *bq2 = (const float*)d_in[11],
              *Wk2 = (const float*)d_in[12], *bk2 = (const float*)d_in[13],
              *Wv2 = (const float*)d_in[14], *bv2 = (const float*)d_in[15],
              *Ws2 = (const float*)d_in[16], *bs2 = (const float*)d_in[17];
  float* out = (float*)d_out;
  const int E = in_sizes[1] / 2;

  char* base = (char*)d_ws;
  size_t off = 0;
  auto take = [&](size_t bytes) {
    char* p = base + off;
    off += (bytes + 255) & ~(size_t)255;
    return p;
  };
  float* B1    = (float*)take((size_t)128 * NC * 4);
  float* bias1 = (float*)take(NC * 4);
  float* B2    = (float*)take((size_t)64 * NC * 4);
  float* bias2 = (float*)take(NC * 4);
  int*   flag  = (int*)take(256);
  int*   deg   = (int*)take((size_t)NN * 4);
  int*   rp    = (int*)take((size_t)(NN + 1) * 4);
  int*   cur   = (int*)take((size_t)(NN + 1) * 4);
  int*   srcs  = (int*)take((size_t)E * 4);
  int*   dsts  = (int*)take((size_t)E * 4);
  int*   col   = (int*)take((size_t)E * 4);
  float* QKVS  = (float*)take((size_t)NN * NC * 4);   // 71.7 MB, reused by both layers
  float* Hbuf  = (float*)take((size_t)NN * CHN * 4);
  (void)ws_size; (void)n_in; (void)out_size;

  // weight packing + edge decode + CSR build (same edge list for both layers)
  hipMemsetAsync(deg, 0, (size_t)NN * 4, stream);
  pack_all<<<(86912 + 255) / 256, 256, 0, stream>>>(
      Wq1, bq1, Wk1, bk1, Wv1, bv1, Ws1, bs1,
      Wq2, bq2, Wk2, bk2, Wv2, bv2, Ws2, bs2, B1, bias1, B2, bias2);
  detect_k<<<1, 64, 0, stream>>>(ei_raw, flag);
  decode_k<<<(E + 255) / 256, 256, 0, stream>>>(ei_raw, flag, srcs, dsts, deg, E);
  scan_k<<<1, 1024, 0, stream>>>(deg, rp, cur, NN);
  scatter_k<<<(E + 255) / 256, 256, 0, stream>>>(srcs, dsts, cur, col, E);

  // layer 1: x[40000x128] -> QKVS -> fused agg -> Hbuf (leaky relu)
  gemm_bias<<<dim3(NC / 64, NN / 64), 256, 0, stream>>>(x, B1, bias1, QKVS, NN, NC, 128);
  agg_fused<<<NN, 128, 0, stream>>>(QKVS, rp, col, Hbuf, 1);

  // layer 2: Hbuf[40000x64] -> QKVS -> fused agg -> out (no activation)
  gemm_bias<<<dim3(NC / 64, NN / 64), 256, 0, stream>>>(Hbuf, B2, bias2, QKVS, NN, NC, 64);
  agg_fused<<<NN, 128, 0, stream>>>(QKVS, rp, col, out, 0);
}

// Round 6
// 438.262 us; speedup vs baseline: 1.3332x; 1.1868x over previous
//
#include <hip/hip_runtime.h>
#include <math.h>

// Problem constants (B=4, N=10000 -> Nn=40000; IN=128, HID=OUT=64, H=2)
#define NN    40000
#define HEADS 2
#define CHN   64
#define NC    448   // packed cols: Q(128) | K(128) | V(128) | S(64)
#define KOFF  128
#define VOFF  256
#define SOFF  384

#define SCAN_BLK 256
#define NBLK ((NN + SCAN_BLK - 1) / SCAN_BLK)   // 157

// ---- edge-index dtype detection: int64 stored LE has zero odd words ----
__global__ void detect_k(const int* __restrict__ w, int* __restrict__ flag) {
  int lane = threadIdx.x & 63;
  int v = 0;
#pragma unroll
  for (int i = 0; i < 4; ++i) v |= w[2 * (lane + 64 * i) + 1];
#pragma unroll
  for (int o = 32; o; o >>= 1) v |= __shfl_xor(v, o);
  if (lane == 0 && blockIdx.x == 0) *flag = (v == 0) ? 1 : 0;
}

// ---- decode edges to int32 srcs/dsts + fused degree histogram ----
__global__ void decode_k(const int* __restrict__ w, const int* __restrict__ flag,
                         int* __restrict__ srcs, int* __restrict__ dsts,
                         int* __restrict__ deg, int E) {
  int e = blockIdx.x * blockDim.x + threadIdx.x;
  if (e >= E) return;
  int s, d;
  if (*flag) { s = w[2 * e]; d = w[2 * (E + e)]; }
  else       { s = w[e];     d = w[E + e]; }
  srcs[e] = s;
  dsts[e] = d;
  atomicAdd(&deg[d], 1);
}

// ---- pack both layers' Wq|Wk|Wv|Ws into B[K][448] (+biases) in ONE launch ----
__global__ void pack_all(const float* __restrict__ Wq1, const float* __restrict__ bq1,
                         const float* __restrict__ Wk1, const float* __restrict__ bk1,
                         const float* __restrict__ Wv1, const float* __restrict__ bv1,
                         const float* __restrict__ Ws1, const float* __restrict__ bs1,
                         const float* __restrict__ Wq2, const float* __restrict__ bq2,
                         const float* __restrict__ Wk2, const float* __restrict__ bk2,
                         const float* __restrict__ Wv2, const float* __restrict__ bv2,
                         const float* __restrict__ Ws2, const float* __restrict__ bs2,
                         float* __restrict__ B1, float* __restrict__ bias1,
                         float* __restrict__ B2, float* __restrict__ bias2) {
  int i = blockIdx.x * blockDim.x + threadIdx.x;
  if (i < 57344) {                    // layer-1 weights [128][448]
    int k = i / NC, c = i % NC;
    float v;
    if (c < 128)      v = Wq1[k * 128 + c];
    else if (c < 256) v = Wk1[k * 128 + (c - 128)];
    else if (c < 384) v = Wv1[k * 128 + (c - 256)];
    else              v = Ws1[k * 64 + (c - 384)];
    B1[i] = v;
  } else if (i < 86016) {             // layer-2 weights [64][448]
    int j = i - 57344;
    int k = j / NC, c = j % NC;
    float v;
    if (c < 128)      v = Wq2[k * 128 + c];
    else if (c < 256) v = Wk2[k * 128 + (c - 128)];
    else if (c < 384) v = Wv2[k * 128 + (c - 256)];
    else              v = Ws2[k * 64 + (c - 384)];
    B2[j] = v;
  } else if (i < 86464) {             // bias1
    int c = i - 86016;
    float v;
    if (c < 128)      v = bq1[c];
    else if (c < 256) v = bk1[c - 128];
    else if (c < 384) v = bv1[c - 256];
    else              v = bs1[c - 384];
    bias1[c] = v;
  } else if (i < 86912) {             // bias2
    int c = i - 86464;
    float v;
    if (c < 128)      v = bq2[c];
    else if (c < 256) v = bk2[c - 128];
    else if (c < 384) v = bv2[c - 256];
    else              v = bs2[c - 384];
    bias2[c] = v;
  }
}

// ---- hierarchical exclusive scan of deg[NN] -> rp[NN+1], cur[NN] ----
// level 1: per-block sums
__global__ __launch_bounds__(SCAN_BLK) void bsum_k(const int* __restrict__ deg,
                                                   int* __restrict__ bsum) {
  int t = threadIdx.x;
  int i = blockIdx.x * SCAN_BLK + t;
  int v = (i < NN) ? deg[i] : 0;
#pragma unroll
  for (int o = 32; o; o >>= 1) v += __shfl_xor(v, o);
  __shared__ int ws[4];
  if ((t & 63) == 0) ws[t >> 6] = v;
  __syncthreads();
  if (t == 0) bsum[blockIdx.x] = ws[0] + ws[1] + ws[2] + ws[3];
}

// level 2: single small block scans the 157 block sums (exclusive)
__global__ __launch_bounds__(SCAN_BLK) void bscan_k(const int* __restrict__ bsum,
                                                    int* __restrict__ boff) {
  int t = threadIdx.x;
  int lane = t & 63, w = t >> 6;
  int v = (t < NBLK) ? bsum[t] : 0;
  int incl = v;
#pragma unroll
  for (int o = 1; o < 64; o <<= 1) {
    int u = __shfl_up(incl, o);
    if (lane >= o) incl += u;
  }
  __shared__ int wsum[4];
  if (lane == 63) wsum[w] = incl;
  __syncthreads();
  int woff = 0;
  for (int j = 0; j < w; ++j) woff += wsum[j];
  if (t < NBLK) boff[t] = woff + incl - v;
}

// level 3: per-block exclusive scan + global offset; writes rp, cur, rp[NN]
__global__ __launch_bounds__(SCAN_BLK) void rpwrite_k(const int* __restrict__ deg,
    const int* __restrict__ boff, int* __restrict__ rp, int* __restrict__ cur) {
  int t = threadIdx.x;
  int i = blockIdx.x * SCAN_BLK + t;
  int v = (i < NN) ? deg[i] : 0;
  int lane = t & 63, w = t >> 6;
  int incl = v;
#pragma unroll
  for (int o = 1; o < 64; o <<= 1) {
    int u = __shfl_up(incl, o);
    if (lane >= o) incl += u;
  }
  __shared__ int wsum[4];
  if (lane == 63) wsum[w] = incl;
  __syncthreads();
  int woff = 0;
  for (int j = 0; j < w; ++j) woff += wsum[j];
  int ex = boff[blockIdx.x] + woff + incl - v;
  if (i < NN) { rp[i] = ex; cur[i] = ex; }
  if (i == NN - 1) rp[NN] = ex + v;   // == E
}

__global__ void scatter_k(const int* __restrict__ srcs, const int* __restrict__ dsts,
                          int* __restrict__ cur, int* __restrict__ col, int E) {
  int e = blockIdx.x * blockDim.x + threadIdx.x;
  if (e < E) {
    int p = atomicAdd(&cur[dsts[e]], 1);
    col[p] = srcs[e];
  }
}

// ---- f32 GEMM with fused bias: C[M][N] = A[M][K] @ B[K][N] + bias ----
// BM=BN=64, BK=32, 256 threads, 4x4 per thread. M%64==0, N%64==0, K%32==0.
__global__ __launch_bounds__(256) void gemm_bias(const float* __restrict__ A,
    const float* __restrict__ Bm, const float* __restrict__ bias,
    float* __restrict__ C, int M, int N, int K) {
  __shared__ __align__(16) float As[32][68];  // [k][m], padded
  __shared__ __align__(16) float Bs[32][64];  // [k][n]
  int bm = blockIdx.y << 6, bn = blockIdx.x << 6;
  int tid = threadIdx.x;
  int tr = (tid >> 4) << 2;   // 0..60
  int tc = (tid & 15) << 2;   // 0..60
  float acc[4][4] = {};
  for (int k0 = 0; k0 < K; k0 += 32) {
#pragma unroll
    for (int t = 0; t < 2; ++t) {
      int i = tid + (t << 8);            // 0..511
      int m = i >> 3, k4 = (i & 7) << 2; // A: 64 rows x 8 float4
      const float4 va = *(const float4*)(A + (size_t)(bm + m) * K + k0 + k4);
      As[k4 + 0][m] = va.x; As[k4 + 1][m] = va.y;
      As[k4 + 2][m] = va.z; As[k4 + 3][m] = va.w;
      int kb = i >> 4, n4 = (i & 15) << 2; // B: 32 rows x 16 float4
      *(float4*)&Bs[kb][n4] = *(const float4*)(Bm + (size_t)(k0 + kb) * N + bn + n4);
    }
    __syncthreads();
#pragma unroll
    for (int kk = 0; kk < 32; ++kk) {
      const float4 av = *(const float4*)&As[kk][tr];
      const float4 bv = *(const float4*)&Bs[kk][tc];
      float a[4] = {av.x, av.y, av.z, av.w};
      float b[4] = {bv.x, bv.y, bv.z, bv.w};
#pragma unroll
      for (int i2 = 0; i2 < 4; ++i2)
#pragma unroll
        for (int j = 0; j < 4; ++j) acc[i2][j] += a[i2] * b[j];
    }
    __syncthreads();
  }
  const float4 bb = *(const float4*)&bias[bn + tc];
#pragma unroll
  for (int i2 = 0; i2 < 4; ++i2) {
    float4 o;
    o.x = acc[i2][0] + bb.x; o.y = acc[i2][1] + bb.y;
    o.z = acc[i2][2] + bb.z; o.w = acc[i2][3] + bb.w;
    *(float4*)(C + (size_t)(bm + tr + i2) * N + bn + tc) = o;
  }
}

// ---- fused edge-softmax aggregation + head-mean + skip (+ leaky relu) ----
// one 128-thread block per dst node; wave h = head h; 4x16-lane groups each
// own one edge stream with independent online-softmax state; float4/lane
// channels; depth-2 K/V prefetch; flash-style butterfly state merge.
__global__ __launch_bounds__(128) void agg_fused(const float* __restrict__ QKVS,
    const int* __restrict__ rp, const int* __restrict__ col,
    float* __restrict__ out, int act) {
  int dst = blockIdx.x;
  int h = threadIdx.x >> 6;    // 0 or 1
  int lane = threadIdx.x & 63;
  int g = lane >> 4;           // group 0..3
  int sl = lane & 15;          // sublane: channels 4*sl .. 4*sl+3
  const float scale = 0.125f;  // 1/sqrt(64)

  float4 q4 = *(const float4*)(QKVS + (size_t)dst * NC + h * 64 + 4 * sl);
  q4.x *= scale; q4.y *= scale; q4.z *= scale; q4.w *= scale;
  const float* __restrict__ base = QKVS + h * 64 + 4 * sl;

  float m = -INFINITY, d = 0.f;
  float4 acc = {0.f, 0.f, 0.f, 0.f};
  int e0 = rp[dst], e1 = rp[dst + 1];

  int e = e0 + g;
  if (e < e1) {
    int sCur = col[e];
    int en = e + 4;
    int sNxt = (en < e1) ? col[en] : sCur;
    const float* rC = base + (size_t)sCur * NC;
    float4 kC = *(const float4*)(rC + KOFF);
    float4 vC = *(const float4*)(rC + VOFF);
    while (true) {
      const float* rN = base + (size_t)sNxt * NC;
      float4 kN = *(const float4*)(rN + KOFF);
      float4 vN = *(const float4*)(rN + VOFF);
      int enn = e + 8;
      int sNN = (enn < e1) ? col[enn] : sNxt;
      float p = q4.x * kC.x + q4.y * kC.y + q4.z * kC.z + q4.w * kC.w;
      p += __shfl_xor(p, 1); p += __shfl_xor(p, 2);
      p += __shfl_xor(p, 4); p += __shfl_xor(p, 8);
      float mn = fmaxf(m, p);
      float corr = __expf(m - mn);   // first edge: exp(-inf)=0
      float w = __expf(p - mn);
      d = d * corr + w;
      acc.x = acc.x * corr + w * vC.x;
      acc.y = acc.y * corr + w * vC.y;
      acc.z = acc.z * corr + w * vC.z;
      acc.w = acc.w * corr + w * vC.w;
      m = mn;
      e += 4;
      if (e >= e1) break;
      kC = kN; vC = vN; sNxt = sNN;
    }
  }

  // merge the 4 group states (butterfly over xor 16, 32 -> allreduce)
#pragma unroll
  for (int o = 16; o <= 32; o <<= 1) {
    float m2 = __shfl_xor(m, o);
    float d2 = __shfl_xor(d, o);
    float ax = __shfl_xor(acc.x, o), ay = __shfl_xor(acc.y, o);
    float az = __shfl_xor(acc.z, o), aw = __shfl_xor(acc.w, o);
    float mn = fmaxf(m, m2);
    float c1 = __expf(fmaxf(m - mn, -88.f));
    float c2 = __expf(fmaxf(m2 - mn, -88.f));
    d = d * c1 + d2 * c2;
    acc.x = acc.x * c1 + ax * c2;
    acc.y = acc.y * c1 + ay * c2;
    acc.z = acc.z * c1 + az * c2;
    acc.w = acc.w * c1 + aw * c2;
    m = mn;
  }
  float inv = 1.0f / fmaxf(d, 1e-16f);
  float4 r = {acc.x * inv, acc.y * inv, acc.z * inv, acc.w * inv};

  __shared__ float s1[64];
  if (h == 1 && g == 0) *(float4*)&s1[4 * sl] = r;
  __syncthreads();
  if (h == 0 && g == 0) {
    const float4 rr = *(const float4*)&s1[4 * sl];
    const float4 sk = *(const float4*)(QKVS + (size_t)dst * NC + SOFF + 4 * sl);
    float4 o;
    o.x = 0.5f * (r.x + rr.x) + sk.x;
    o.y = 0.5f * (r.y + rr.y) + sk.y;
    o.z = 0.5f * (r.z + rr.z) + sk.z;
    o.w = 0.5f * (r.w + rr.w) + sk.w;
    if (act) {
      o.x = o.x > 0.f ? o.x : 0.1f * o.x;
      o.y = o.y > 0.f ? o.y : 0.1f * o.y;
      o.z = o.z > 0.f ? o.z : 0.1f * o.z;
      o.w = o.w > 0.f ? o.w : 0.1f * o.w;
    }
    *(float4*)(out + (size_t)dst * CHN + 4 * sl) = o;
  }
}

extern "C" void kernel_launch(void* const* d_in, const int* in_sizes, int n_in,
                              void* d_out, int out_size, void* d_ws, size_t ws_size,
                              hipStream_t stream) {
  const float* x = (const float*)d_in[0];
  const int* ei_raw = (const int*)d_in[1];   // int32 OR int64 (runtime-detected)
  const float *Wq1 = (const float*)d_in[2],  *bq1 = (const float*)d_in[3],
              *Wk1 = (const float*)d_in[4],  *bk1 = (const float*)d_in[5],
              *Wv1 = (const float*)d_in[6],  *bv1 = (const float*)d_in[7],
              *Ws1 = (const float*)d_in[8],  *bs1 = (const float*)d_in[9],
              *Wq2 = (const float*)d_in[10], *bq2 = (const float*)d_in[11],
              *Wk2 = (const float*)d_in[12], *bk2 = (const float*)d_in[13],
              *Wv2 = (const float*)d_in[14], *bv2 = (const float*)d_in[15],
              *Ws2 = (const float*)d_in[16], *bs2 = (const float*)d_in[17];
  float* out = (float*)d_out;
  const int E = in_sizes[1] / 2;

  char* base = (char*)d_ws;
  size_t off = 0;
  auto take = [&](size_t bytes) {
    char* p = base + off;
    off += (bytes + 255) & ~(size_t)255;
    return p;
  };
  float* B1    = (float*)take((size_t)128 * NC * 4);
  float* bias1 = (float*)take(NC * 4);
  float* B2    = (float*)take((size_t)64 * NC * 4);
  float* bias2 = (float*)take(NC * 4);
  int*   flag  = (int*)take(256);
  int*   deg   = (int*)take((size_t)NN * 4);
  int*   rp    = (int*)take((size_t)(NN + 1) * 4);
  int*   cur   = (int*)take((size_t)(NN + 1) * 4);
  int*   bsum  = (int*)take((size_t)NBLK * 4);
  int*   boff  = (int*)take((size_t)NBLK * 4);
  int*   srcs  = (int*)take((size_t)E * 4);
  int*   dsts  = (int*)take((size_t)E * 4);
  int*   col   = (int*)take((size_t)E * 4);
  float* QKVS  = (float*)take((size_t)NN * NC * 4);   // 71.7 MB, reused by both layers
  float* Hbuf  = (float*)take((size_t)NN * CHN * 4);
  (void)ws_size; (void)n_in; (void)out_size;

  // weight packing + edge decode + CSR build (same edge list for both layers)
  hipMemsetAsync(deg, 0, (size_t)NN * 4, stream);
  pack_all<<<(86912 + 255) / 256, 256, 0, stream>>>(
      Wq1, bq1, Wk1, bk1, Wv1, bv1, Ws1, bs1,
      Wq2, bq2, Wk2, bk2, Wv2, bv2, Ws2, bs2, B1, bias1, B2, bias2);
  detect_k<<<1, 64, 0, stream>>>(ei_raw, flag);
  decode_k<<<(E + 255) / 256, 256, 0, stream>>>(ei_raw, flag, srcs, dsts, deg, E);
  bsum_k<<<NBLK, SCAN_BLK, 0, stream>>>(deg, bsum);
  bscan_k<<<1, SCAN_BLK, 0, stream>>>(bsum, boff);
  rpwrite_k<<<NBLK, SCAN_BLK, 0, stream>>>(deg, boff, rp, cur);
  scatter_k<<<(E + 255) / 256, 256, 0, stream>>>(srcs, dsts, cur, col, E);

  // layer 1: x[40000x128] -> QKVS -> fused agg -> Hbuf (leaky relu)
  gemm_bias<<<dim3(NC / 64, NN / 64), 256, 0, stream>>>(x, B1, bias1, QKVS, NN, NC, 128);
  agg_fused<<<NN, 128, 0, stream>>>(QKVS, rp, col, Hbuf, 1);

  // layer 2: Hbuf[40000x64] -> QKVS -> fused agg -> out (no activation)
  gemm_bias<<<dim3(NC / 64, NN / 64), 256, 0, stream>>>(Hbuf, B2, bias2, QKVS, NN, NC, 64);
  agg_fused<<<NN, 128, 0, stream>>>(QKVS, rp, col, out, 0);
}

// Round 7
// 362.573 us; speedup vs baseline: 1.6115x; 1.2088x over previous
//
#include <hip/hip_runtime.h>
#include <math.h>

// Problem constants (B=4, N=10000 -> Nn=40000; IN=128, HID=OUT=64, H=2)
#define NN    40000
#define HEADS 2
#define CHN   64
#define NC    448   // gemm cols: Q(128) | K(128) | V(128) | S(64)
#define QSC   192   // QS table cols: Q(128) | S(64)

#define SCAN_BLK 256
#define NBLK ((NN + SCAN_BLK - 1) / SCAN_BLK)   // 157

__device__ __forceinline__ unsigned short f2bf(float f) {   // RNE f32->bf16
  unsigned int u = __float_as_uint(f);
  unsigned int r = u + 0x7fffu + ((u >> 16) & 1u);
  return (unsigned short)(r >> 16);
}

// ---- edge-index dtype detection: int64 stored LE has zero odd words ----
__global__ void detect_k(const int* __restrict__ w, int* __restrict__ flag) {
  int lane = threadIdx.x & 63;
  int v = 0;
#pragma unroll
  for (int i = 0; i < 4; ++i) v |= w[2 * (lane + 64 * i) + 1];
#pragma unroll
  for (int o = 32; o; o >>= 1) v |= __shfl_xor(v, o);
  if (lane == 0 && blockIdx.x == 0) *flag = (v == 0) ? 1 : 0;
}

// ---- decode edges to int32 srcs/dsts + fused degree histogram ----
__global__ void decode_k(const int* __restrict__ w, const int* __restrict__ flag,
                         int* __restrict__ srcs, int* __restrict__ dsts,
                         int* __restrict__ deg, int E) {
  int e = blockIdx.x * blockDim.x + threadIdx.x;
  if (e >= E) return;
  int s, d;
  if (*flag) { s = w[2 * e]; d = w[2 * (E + e)]; }
  else       { s = w[e];     d = w[E + e]; }
  srcs[e] = s;
  dsts[e] = d;
  atomicAdd(&deg[d], 1);
}

// ---- pack both layers' Wq|Wk|Wv|Ws into B[K][448] (+biases) in ONE launch ----
__global__ void pack_all(const float* __restrict__ Wq1, const float* __restrict__ bq1,
                         const float* __restrict__ Wk1, const float* __restrict__ bk1,
                         const float* __restrict__ Wv1, const float* __restrict__ bv1,
                         const float* __restrict__ Ws1, const float* __restrict__ bs1,
                         const float* __restrict__ Wq2, const float* __restrict__ bq2,
                         const float* __restrict__ Wk2, const float* __restrict__ bk2,
                         const float* __restrict__ Wv2, const float* __restrict__ bv2,
                         const float* __restrict__ Ws2, const float* __restrict__ bs2,
                         float* __restrict__ B1, float* __restrict__ bias1,
                         float* __restrict__ B2, float* __restrict__ bias2) {
  int i = blockIdx.x * blockDim.x + threadIdx.x;
  if (i < 57344) {                    // layer-1 weights [128][448]
    int k = i / NC, c = i % NC;
    float v;
    if (c < 128)      v = Wq1[k * 128 + c];
    else if (c < 256) v = Wk1[k * 128 + (c - 128)];
    else if (c < 384) v = Wv1[k * 128 + (c - 256)];
    else              v = Ws1[k * 64 + (c - 384)];
    B1[i] = v;
  } else if (i < 86016) {             // layer-2 weights [64][448]
    int j = i - 57344;
    int k = j / NC, c = j % NC;
    float v;
    if (c < 128)      v = Wq2[k * 128 + c];
    else if (c < 256) v = Wk2[k * 128 + (c - 128)];
    else if (c < 384) v = Wv2[k * 128 + (c - 256)];
    else              v = Ws2[k * 64 + (c - 384)];
    B2[j] = v;
  } else if (i < 86464) {             // bias1
    int c = i - 86016;
    float v;
    if (c < 128)      v = bq1[c];
    else if (c < 256) v = bk1[c - 128];
    else if (c < 384) v = bv1[c - 256];
    else              v = bs1[c - 384];
    bias1[c] = v;
  } else if (i < 86912) {             // bias2
    int c = i - 86464;
    float v;
    if (c < 128)      v = bq2[c];
    else if (c < 256) v = bk2[c - 128];
    else if (c < 384) v = bv2[c - 256];
    else              v = bs2[c - 384];
    bias2[c] = v;
  }
}

// ---- hierarchical exclusive scan of deg[NN] -> rp[NN+1], cur[NN] ----
__global__ __launch_bounds__(SCAN_BLK) void bsum_k(const int* __restrict__ deg,
                                                   int* __restrict__ bsum) {
  int t = threadIdx.x;
  int i = blockIdx.x * SCAN_BLK + t;
  int v = (i < NN) ? deg[i] : 0;
#pragma unroll
  for (int o = 32; o; o >>= 1) v += __shfl_xor(v, o);
  __shared__ int ws[4];
  if ((t & 63) == 0) ws[t >> 6] = v;
  __syncthreads();
  if (t == 0) bsum[blockIdx.x] = ws[0] + ws[1] + ws[2] + ws[3];
}

__global__ __launch_bounds__(SCAN_BLK) void bscan_k(const int* __restrict__ bsum,
                                                    int* __restrict__ boff) {
  int t = threadIdx.x;
  int lane = t & 63, w = t >> 6;
  int v = (t < NBLK) ? bsum[t] : 0;
  int incl = v;
#pragma unroll
  for (int o = 1; o < 64; o <<= 1) {
    int u = __shfl_up(incl, o);
    if (lane >= o) incl += u;
  }
  __shared__ int wsum[4];
  if (lane == 63) wsum[w] = incl;
  __syncthreads();
  int woff = 0;
  for (int j = 0; j < w; ++j) woff += wsum[j];
  if (t < NBLK) boff[t] = woff + incl - v;
}

__global__ __launch_bounds__(SCAN_BLK) void rpwrite_k(const int* __restrict__ deg,
    const int* __restrict__ boff, int* __restrict__ rp, int* __restrict__ cur) {
  int t = threadIdx.x;
  int i = blockIdx.x * SCAN_BLK + t;
  int v = (i < NN) ? deg[i] : 0;
  int lane = t & 63, w = t >> 6;
  int incl = v;
#pragma unroll
  for (int o = 1; o < 64; o <<= 1) {
    int u = __shfl_up(incl, o);
    if (lane >= o) incl += u;
  }
  __shared__ int wsum[4];
  if (lane == 63) wsum[w] = incl;
  __syncthreads();
  int woff = 0;
  for (int j = 0; j < w; ++j) woff += wsum[j];
  int ex = boff[blockIdx.x] + woff + incl - v;
  if (i < NN) { rp[i] = ex; cur[i] = ex; }
  if (i == NN - 1) rp[NN] = ex + v;   // == E
}

__global__ void scatter_k(const int* __restrict__ srcs, const int* __restrict__ dsts,
                          int* __restrict__ cur, int* __restrict__ col, int E) {
  int e = blockIdx.x * blockDim.x + threadIdx.x;
  if (e < E) {
    int p = atomicAdd(&cur[dsts[e]], 1);
    col[p] = srcs[e];
  }
}

// ---- f32 GEMM (fused bias) with routed epilogue ----
// C cols: [0,128) -> QS f32 Q | [128,256) -> KVH bf16 K | [256,384) -> KVH bf16 V
//         [384,448) -> QS f32 S.  KVH row: [head][group g:k4|v4] = 256 ushort.
__global__ __launch_bounds__(256) void gemm_bias(const float* __restrict__ A,
    const float* __restrict__ Bm, const float* __restrict__ bias,
    float* __restrict__ QS, unsigned short* __restrict__ KVH, int M, int K) {
  __shared__ __align__(16) float As[32][68];  // [k][m], padded
  __shared__ __align__(16) float Bs[32][64];  // [k][n]
  int bm = blockIdx.y << 6, bn = blockIdx.x << 6;
  int tid = threadIdx.x;
  int tr = (tid >> 4) << 2;   // 0..60
  int tc = (tid & 15) << 2;   // 0..60
  float acc[4][4] = {};
  for (int k0 = 0; k0 < K; k0 += 32) {
#pragma unroll
    for (int t = 0; t < 2; ++t) {
      int i = tid + (t << 8);            // 0..511
      int m = i >> 3, k4 = (i & 7) << 2; // A: 64 rows x 8 float4
      const float4 va = *(const float4*)(A + (size_t)(bm + m) * K + k0 + k4);
      As[k4 + 0][m] = va.x; As[k4 + 1][m] = va.y;
      As[k4 + 2][m] = va.z; As[k4 + 3][m] = va.w;
      int kb = i >> 4, n4 = (i & 15) << 2; // B: 32 rows x 16 float4
      *(float4*)&Bs[kb][n4] = *(const float4*)(Bm + (size_t)(k0 + kb) * NC + bn + n4);
    }
    __syncthreads();
#pragma unroll
    for (int kk = 0; kk < 32; ++kk) {
      const float4 av = *(const float4*)&As[kk][tr];
      const float4 bv = *(const float4*)&Bs[kk][tc];
      float a[4] = {av.x, av.y, av.z, av.w};
      float b[4] = {bv.x, bv.y, bv.z, bv.w};
#pragma unroll
      for (int i2 = 0; i2 < 4; ++i2)
#pragma unroll
        for (int j = 0; j < 4; ++j) acc[i2][j] += a[i2] * b[j];
    }
    __syncthreads();
  }
  const int c0 = bn + tc;
  const float4 bb = *(const float4*)&bias[c0];
#pragma unroll
  for (int i2 = 0; i2 < 4; ++i2) {
    int row = bm + tr + i2;
    float4 o;
    o.x = acc[i2][0] + bb.x; o.y = acc[i2][1] + bb.y;
    o.z = acc[i2][2] + bb.z; o.w = acc[i2][3] + bb.w;
    if (c0 < 128) {
      *(float4*)(QS + (size_t)row * QSC + c0) = o;
    } else if (c0 < 384) {
      int isV = (c0 >= 256);
      int kc = c0 - 128 - (isV << 7);       // 0..127
      int hh = kc >> 6, ch = kc & 63;
      size_t off = (size_t)row * 256 + hh * 128 + (ch >> 2) * 8 + (isV << 2);
      ushort4 w4;
      w4.x = f2bf(o.x); w4.y = f2bf(o.y); w4.z = f2bf(o.z); w4.w = f2bf(o.w);
      *(ushort4*)(KVH + off) = w4;
    } else {
      *(float4*)(QS + (size_t)row * QSC + 128 + (c0 - 384)) = o;
    }
  }
}

// ---- fused edge-softmax aggregation + head-mean + skip (+ leaky relu) ----
// one 128-thread block per dst; wave h = head h; 4x16-lane groups, each owns
// an edge stream with its own online-softmax state. Per edge-head-lane: ONE
// 16B load (4 bf16 K + 4 bf16 V). Depth-2 prefetch; butterfly state merge.
__global__ __launch_bounds__(128) void agg_fused(const float* __restrict__ QS,
    const unsigned short* __restrict__ KVH,
    const int* __restrict__ rp, const int* __restrict__ col,
    float* __restrict__ out, int act) {
  int dst = blockIdx.x;
  int h = threadIdx.x >> 6;    // 0 or 1
  int lane = threadIdx.x & 63;
  int g = lane >> 4;           // group 0..3
  int sl = lane & 15;          // sublane: channels 4*sl .. 4*sl+3
  const float scale = 0.125f;  // 1/sqrt(64)

  float4 q4 = *(const float4*)(QS + (size_t)dst * QSC + h * 64 + 4 * sl);
  q4.x *= scale; q4.y *= scale; q4.z *= scale; q4.w *= scale;
  const unsigned short* __restrict__ kvb = KVH + h * 128 + sl * 8;

  float m = -INFINITY, d = 0.f;
  float4 acc = {0.f, 0.f, 0.f, 0.f};
  int e0 = rp[dst], e1 = rp[dst + 1];

  int e = e0 + g;
  if (e < e1) {
    int sCur = col[e];
    int en = e + 4;
    int sNxt = (en < e1) ? col[en] : sCur;
    uint4 uC = *(const uint4*)(kvb + (size_t)sCur * 256);
    while (true) {
      uint4 uN = *(const uint4*)(kvb + (size_t)sNxt * 256);
      int enn = e + 8;
      int sNN = (enn < e1) ? col[enn] : sNxt;
      // unpack K (low/high bf16 of each dword)
      float k0 = __uint_as_float(uC.x << 16);
      float k1 = __uint_as_float(uC.x & 0xffff0000u);
      float k2 = __uint_as_float(uC.y << 16);
      float k3 = __uint_as_float(uC.y & 0xffff0000u);
      float p = q4.x * k0 + q4.y * k1 + q4.z * k2 + q4.w * k3;
      p += __shfl_xor(p, 1); p += __shfl_xor(p, 2);
      p += __shfl_xor(p, 4); p += __shfl_xor(p, 8);
      float mn = fmaxf(m, p);
      float corr = __expf(m - mn);   // first edge: exp(-inf)=0
      float w = __expf(p - mn);
      float v0 = __uint_as_float(uC.z << 16);
      float v1 = __uint_as_float(uC.z & 0xffff0000u);
      float v2 = __uint_as_float(uC.w << 16);
      float v3 = __uint_as_float(uC.w & 0xffff0000u);
      d = d * corr + w;
      acc.x = acc.x * corr + w * v0;
      acc.y = acc.y * corr + w * v1;
      acc.z = acc.z * corr + w * v2;
      acc.w = acc.w * corr + w * v3;
      m = mn;
      e += 4;
      if (e >= e1) break;
      uC = uN; sNxt = sNN;
    }
  }

  // merge the 4 group states (butterfly over xor 16, 32 -> allreduce)
#pragma unroll
  for (int o = 16; o <= 32; o <<= 1) {
    float m2 = __shfl_xor(m, o);
    float d2 = __shfl_xor(d, o);
    float ax = __shfl_xor(acc.x, o), ay = __shfl_xor(acc.y, o);
    float az = __shfl_xor(acc.z, o), aw = __shfl_xor(acc.w, o);
    float mn = fmaxf(m, m2);
    float c1 = __expf(fmaxf(m - mn, -88.f));   // NaN-guard for empty groups
    float c2 = __expf(fmaxf(m2 - mn, -88.f));
    d = d * c1 + d2 * c2;
    acc.x = acc.x * c1 + ax * c2;
    acc.y = acc.y * c1 + ay * c2;
    acc.z = acc.z * c1 + az * c2;
    acc.w = acc.w * c1 + aw * c2;
    m = mn;
  }
  float inv = 1.0f / fmaxf(d, 1e-16f);
  float4 r = {acc.x * inv, acc.y * inv, acc.z * inv, acc.w * inv};

  __shared__ float s1[64];
  if (h == 1 && g == 0) *(float4*)&s1[4 * sl] = r;
  __syncthreads();
  if (h == 0 && g == 0) {
    const float4 rr = *(const float4*)&s1[4 * sl];
    const float4 sk = *(const float4*)(QS + (size_t)dst * QSC + 128 + 4 * sl);
    float4 o;
    o.x = 0.5f * (r.x + rr.x) + sk.x;
    o.y = 0.5f * (r.y + rr.y) + sk.y;
    o.z = 0.5f * (r.z + rr.z) + sk.z;
    o.w = 0.5f * (r.w + rr.w) + sk.w;
    if (act) {
      o.x = o.x > 0.f ? o.x : 0.1f * o.x;
      o.y = o.y > 0.f ? o.y : 0.1f * o.y;
      o.z = o.z > 0.f ? o.z : 0.1f * o.z;
      o.w = o.w > 0.f ? o.w : 0.1f * o.w;
    }
    *(float4*)(out + (size_t)dst * CHN + 4 * sl) = o;
  }
}

extern "C" void kernel_launch(void* const* d_in, const int* in_sizes, int n_in,
                              void* d_out, int out_size, void* d_ws, size_t ws_size,
                              hipStream_t stream) {
  const float* x = (const float*)d_in[0];
  const int* ei_raw = (const int*)d_in[1];   // int32 OR int64 (runtime-detected)
  const float *Wq1 = (const float*)d_in[2],  *bq1 = (const float*)d_in[3],
              *Wk1 = (const float*)d_in[4],  *bk1 = (const float*)d_in[5],
              *Wv1 = (const float*)d_in[6],  *bv1 = (const float*)d_in[7],
              *Ws1 = (const float*)d_in[8],  *bs1 = (const float*)d_in[9],
              *Wq2 = (const float*)d_in[10], *bq2 = (const float*)d_in[11],
              *Wk2 = (const float*)d_in[12], *bk2 = (const float*)d_in[13],
              *Wv2 = (const float*)d_in[14], *bv2 = (const float*)d_in[15],
              *Ws2 = (const float*)d_in[16], *bs2 = (const float*)d_in[17];
  float* out = (float*)d_out;
  const int E = in_sizes[1] / 2;

  char* base = (char*)d_ws;
  size_t off = 0;
  auto take = [&](size_t bytes) {
    char* p = base + off;
    off += (bytes + 255) & ~(size_t)255;
    return p;
  };
  float* B1    = (float*)take((size_t)128 * NC * 4);
  float* bias1 = (float*)take(NC * 4);
  float* B2    = (float*)take((size_t)64 * NC * 4);
  float* bias2 = (float*)take(NC * 4);
  int*   flag  = (int*)take(256);
  int*   deg   = (int*)take((size_t)NN * 4);
  int*   rp    = (int*)take((size_t)(NN + 1) * 4);
  int*   cur   = (int*)take((size_t)(NN + 1) * 4);
  int*   bsum  = (int*)take((size_t)NBLK * 4);
  int*   boff  = (int*)take((size_t)NBLK * 4);
  int*   srcs  = (int*)take((size_t)E * 4);
  int*   dsts  = (int*)take((size_t)E * 4);
  int*   col   = (int*)take((size_t)E * 4);
  float* QS    = (float*)take((size_t)NN * QSC * 4);            // 30.7 MB
  unsigned short* KVH = (unsigned short*)take((size_t)NN * 256 * 2);  // 20.5 MB
  float* Hbuf  = (float*)take((size_t)NN * CHN * 4);
  (void)ws_size; (void)n_in; (void)out_size;

  // weight packing + edge decode + CSR build (same edge list for both layers)
  hipMemsetAsync(deg, 0, (size_t)NN * 4, stream);
  pack_all<<<(86912 + 255) / 256, 256, 0, stream>>>(
      Wq1, bq1, Wk1, bk1, Wv1, bv1, Ws1, bs1,
      Wq2, bq2, Wk2, bk2, Wv2, bv2, Ws2, bs2, B1, bias1, B2, bias2);
  detect_k<<<1, 64, 0, stream>>>(ei_raw, flag);
  decode_k<<<(E + 255) / 256, 256, 0, stream>>>(ei_raw, flag, srcs, dsts, deg, E);
  bsum_k<<<NBLK, SCAN_BLK, 0, stream>>>(deg, bsum);
  bscan_k<<<1, SCAN_BLK, 0, stream>>>(bsum, boff);
  rpwrite_k<<<NBLK, SCAN_BLK, 0, stream>>>(deg, boff, rp, cur);
  scatter_k<<<(E + 255) / 256, 256, 0, stream>>>(srcs, dsts, cur, col, E);

  // layer 1: x[40000x128] -> QS/KVH -> fused agg -> Hbuf (leaky relu)
  gemm_bias<<<dim3(NC / 64, NN / 64), 256, 0, stream>>>(x, B1, bias1, QS, KVH, NN, 128);
  agg_fused<<<NN, 128, 0, stream>>>(QS, KVH, rp, col, Hbuf, 1);

  // layer 2: Hbuf[40000x64] -> QS/KVH -> fused agg -> out (no activation)
  gemm_bias<<<dim3(NC / 64, NN / 64), 256, 0, stream>>>(Hbuf, B2, bias2, QS, KVH, NN, 64);
  agg_fused<<<NN, 128, 0, stream>>>(QS, KVH, rp, col, out, 0);
}